// Round 12
// baseline (188.850 us; speedup 1.0000x reference)
//
#include <hip/hip_runtime.h>
#include <hip/hip_bf16.h>
#include <math.h>

#define N_NODES 80000
#define N_EDGES 1280000
#define IN_C 128
#define HID_C 64
#define OUT_C 40

// Bucketed counting sort: bucket = dst >> 8 (256 nodes per bucket)
#define KB 313            // ceil(80000 / 256)
#define BK_CAP 4600       // capacity per bucket (mean 4090, sigma ~64 -> 8 sigma)
#define EPT_A 8           // edges per thread in phase A (512 thr -> 4096 per WG)
#define BINA_BLOCKS 313   // ceil(N_EDGES / 4096)
#define GEMM1_BLOCKS 625  // N_NODES / 128

// ---- bf16 helpers (storage bf16, math fp32) ----
__device__ __forceinline__ float bf_lo(unsigned u) {
    union { unsigned i; float f; } c; c.i = u << 16; return c.f;
}
__device__ __forceinline__ float bf_hi(unsigned u) {
    union { unsigned i; float f; } c; c.i = u & 0xffff0000u; return c.f;
}
__device__ __forceinline__ unsigned pack_bf2(float a, float b) {  // RTNE
    union { float f; unsigned i; } ca, cb; ca.f = a; cb.f = b;
    unsigned ra = (ca.i + 0x7fffu + ((ca.i >> 16) & 1u)) >> 16;
    unsigned rb = (cb.i + 0x7fffu + ((cb.i >> 16) & 1u)) >> 16;
    return ra | (rb << 16);
}

typedef short v8s __attribute__((ext_vector_type(8)));   // 8 bf16 = 4 VGPR
typedef float v4f __attribute__((ext_vector_type(4)));
typedef float v2f __attribute__((ext_vector_type(2)));
union U16 { uint4 u; v8s s; };

__device__ __forceinline__ v2f bf2f(unsigned u) {        // unpack pair -> float2
    return (v2f){bf_lo(u), bf_hi(u)};
}

// ======== prep: W1^T, W2^T to bf16 + zero bcnt (16 blocks) ========
__global__ void prep_w_kernel(const float* __restrict__ W1, const float* __restrict__ W2,
                              unsigned* __restrict__ w1t, unsigned* __restrict__ w2t,
                              int* __restrict__ bcnt) {
    const int g = blockIdx.x * 256 + threadIdx.x;     // 0..4095
    if (g < KB) bcnt[g] = 0;
    {   // w1t: 4096 entries, one per g
        const int wcol = g >> 6, kk = g & 63;
        w1t[g] = pack_bf2(W1[(2 * kk) * HID_C + wcol], W1[(2 * kk + 1) * HID_C + wcol]);
    }
    if (g < 1536) {   // w2t
        const int wcol = g >> 5, kk = g & 31;
        w2t[g] = (wcol < OUT_C)
            ? pack_bf2(W2[(2 * kk) * OUT_C + wcol], W2[(2 * kk + 1) * OUT_C + wcol])
            : 0u;
    }
}

// ========== MERGED: binA (blocks 0..312) + GEMM1 (blocks 313..937) ==========
__global__ __launch_bounds__(512) void binA_gemm1_kernel(
        const int* __restrict__ src, const int* __restrict__ dst,
        int* __restrict__ bcnt, int* __restrict__ gbuf,
        const float* __restrict__ x, const unsigned* __restrict__ w1t,
        unsigned* __restrict__ h1b) {
    __shared__ int lcnt[KB];
    __shared__ int lexcl[KB];
    __shared__ int lbase[KB];
    __shared__ int lcur[KB];
    __shared__ int stage[512 * EPT_A];
    __shared__ int gaddr[512 * EPT_A];
    const int tid = threadIdx.x;

    if (blockIdx.x >= BINA_BLOCKS) {
        // ---------------- GEMM1 (MFMA): h1b = bf16(x @ W1) ----------------
        const int bid = blockIdx.x - BINA_BLOCKS;
        const int wave = tid >> 6, lane = tid & 63;
        const int nl = lane & 15, quad = lane >> 4;
        const int node = (bid * 8 + wave) * 16 + nl;

        v4f acc[4];
#pragma unroll
        for (int q = 0; q < 4; ++q) acc[q] = (v4f){0.f, 0.f, 0.f, 0.f};

#pragma unroll
        for (int kit = 0; kit < 4; ++kit) {
            const float* xp = x + (size_t)node * IN_C + kit * 32 + quad * 8;
            const float4 lo = *(const float4*)xp;
            const float4 hi = *(const float4*)(xp + 4);
            U16 bu;
            bu.u.x = pack_bf2(lo.x, lo.y); bu.u.y = pack_bf2(lo.z, lo.w);
            bu.u.z = pack_bf2(hi.x, hi.y); bu.u.w = pack_bf2(hi.z, hi.w);
#pragma unroll
            for (int mt = 0; mt < 4; ++mt) {
                U16 au;
                au.u = *(const uint4*)(w1t + ((mt * 16 + nl) * 64 + kit * 16 + quad * 4));
                acc[mt] = __builtin_amdgcn_mfma_f32_16x16x32_bf16(au.s, bu.s, acc[mt], 0, 0, 0);
            }
        }
#pragma unroll
        for (int mt = 0; mt < 4; ++mt) {
            uint2 o;
            o.x = pack_bf2(acc[mt][0], acc[mt][1]);
            o.y = pack_bf2(acc[mt][2], acc[mt][3]);
            *(uint2*)(h1b + (size_t)node * 32 + mt * 8 + quad * 2) = o;
        }
        return;
    }

    // ---------------- binA: bin edges by dst>>8, grouped writes ----------------
    for (int i = tid; i < KB; i += 512) lcnt[i] = 0;
    __syncthreads();

    const int e0 = blockIdx.x * 512 * EPT_A;
    int my_s[EPT_A], my_b[EPT_A], my_dl[EPT_A];
#pragma unroll
    for (int j = 0; j < EPT_A; ++j) {
        const int e = e0 + j * 512 + tid;
        if (e < N_EDGES) {
            const int d = dst[e];
            my_s[j] = src[e];
            my_b[j] = d >> 8;
            my_dl[j] = d & 255;
            atomicAdd(&lcnt[my_b[j]], 1);
        } else my_b[j] = -1;
    }
    __syncthreads();

    if (tid < KB) lexcl[tid] = lcnt[tid];
    __syncthreads();
    for (int o = 1; o < KB; o <<= 1) {
        int t = (tid < KB && tid >= o) ? lexcl[tid - o] : 0;
        __syncthreads();
        if (tid < KB) lexcl[tid] += t;
        __syncthreads();
    }
    const int total = lexcl[KB - 1];
    if (tid < KB) {
        lexcl[tid] -= lcnt[tid];
        lbase[tid] = (lcnt[tid] > 0) ? atomicAdd(&bcnt[tid], lcnt[tid]) : 0;
        lcur[tid] = 0;
    }
    __syncthreads();

#pragma unroll
    for (int j = 0; j < EPT_A; ++j) {
        if (my_b[j] >= 0) {
            const int b = my_b[j];
            const int r = atomicAdd(&lcur[b], 1);
            const int li = lexcl[b] + r;
            stage[li] = (my_s[j] << 8) | my_dl[j];
            int gp = lbase[b] + r;
            if (gp >= BK_CAP) gp = BK_CAP - 1;
            gaddr[li] = b * BK_CAP + gp;
        }
    }
    __syncthreads();

    for (int i = tid; i < total; i += 512)
        gbuf[gaddr[i]] = stage[i];
}

// ===== Phase B: per-bucket -> rp + col (coalesced); bases scanned in-block =====
__global__ __launch_bounds__(512) void binB_kernel(const int* __restrict__ bcnt,
                                                   const int* __restrict__ gbuf,
                                                   int* __restrict__ rp,
                                                   int* __restrict__ col) {
    __shared__ int sc[KB];
    __shared__ int hist[256];
    __shared__ int excl[256];
    __shared__ int cur[256];
    __shared__ int outb[BK_CAP];
    const int b = blockIdx.x;
    const int tid = threadIdx.x;

    if (tid < KB) sc[tid] = min(bcnt[tid], BK_CAP);
    __syncthreads();
    for (int o = 1; o < KB; o <<= 1) {
        int t = (tid < KB && tid >= o) ? sc[tid - o] : 0;
        __syncthreads();
        if (tid < KB) sc[tid] += t;
        __syncthreads();
    }
    const int n = min(bcnt[b], BK_CAP);
    const int cbase = sc[b] - n;
    const int* __restrict__ my = gbuf + (size_t)b * BK_CAP;

    if (tid < 256) hist[tid] = 0;
    __syncthreads();
    for (int i = tid; i < n; i += 512)
        atomicAdd(&hist[my[i] & 255], 1);
    __syncthreads();

    int h = 0;
    if (tid < 256) { h = hist[tid]; excl[tid] = h; }
    __syncthreads();
    for (int o = 1; o < 256; o <<= 1) {
        int t = (tid < 256 && tid >= o) ? excl[tid - o] : 0;
        __syncthreads();
        if (tid < 256) excl[tid] += t;
        __syncthreads();
    }
    if (tid < 256) {
        const int ex = excl[tid] - h;   // exclusive
        cur[tid] = ex;
        const int node = b * 256 + tid;
        if (node <= N_NODES) rp[node] = cbase + ex;
    }
    __syncthreads();

    for (int i = tid; i < n; i += 512) {
        const int pk = my[i];
        const int pos = atomicAdd(&cur[pk & 255], 1);
        outb[pos] = pk >> 8;
    }
    __syncthreads();
    for (int i = tid; i < n; i += 512)
        col[cbase + i] = outb[i];
}

// ===== SpMM1 gather: 2 nodes/wave (32 lanes = 4 edge slots x 8 lanes x uint4) =====
// Direct per-lane col loads (same-address merge) -> 8 independent col->h1 chains.
__global__ void gather64_kernel(const int* __restrict__ rp, const int* __restrict__ col,
                                const unsigned* __restrict__ h1b,
                                unsigned* __restrict__ agg1b) {
    const int lane = threadIdx.x & 63;
    const int wave = threadIdx.x >> 6;
    const int sl = lane & 31;          // sub-lane within node group
    const int es = sl >> 3;            // edge slot 0..3
    const int cl = sl & 7;             // channel group (uint4 = 8 ch)
    const int node = blockIdx.x * 8 + wave * 2 + (lane >> 5);
    const int b = rp[node], e = rp[node + 1];

    v2f acc[4];
#pragma unroll
    for (int k = 0; k < 4; ++k) acc[k] = (v2f){0.f, 0.f};

    for (int pos = b; __any(pos < e); pos += 32) {
#pragma unroll
        for (int j = 0; j < 8; ++j) {
            const int ei = pos + (j << 2) + es;
            if (ei < e) {
                const int s = col[ei];
                const uint4 v = *(const uint4*)(h1b + (size_t)s * 32 + cl * 4);
                acc[0] += bf2f(v.x); acc[1] += bf2f(v.y);
                acc[2] += bf2f(v.z); acc[3] += bf2f(v.w);
            }
        }
    }
    // fold 4 edge-slots -> slot 0 (lanes sl<8), within each 32-lane group
#pragma unroll
    for (int k = 0; k < 4; ++k) {
        acc[k][0] += __shfl_down(acc[k][0], 16, 64);
        acc[k][1] += __shfl_down(acc[k][1], 16, 64);
    }
#pragma unroll
    for (int k = 0; k < 4; ++k) {
        acc[k][0] += __shfl_down(acc[k][0], 8, 64);
        acc[k][1] += __shfl_down(acc[k][1], 8, 64);
    }

    if (sl < 8) {   // relu fused (agg only feeds relu->W2)
        uint4 o;
        o.x = pack_bf2(fmaxf(acc[0][0], 0.f), fmaxf(acc[0][1], 0.f));
        o.y = pack_bf2(fmaxf(acc[1][0], 0.f), fmaxf(acc[1][1], 0.f));
        o.z = pack_bf2(fmaxf(acc[2][0], 0.f), fmaxf(acc[2][1], 0.f));
        o.w = pack_bf2(fmaxf(acc[3][0], 0.f), fmaxf(acc[3][1], 0.f));
        *(uint4*)(agg1b + (size_t)node * 32 + cl * 4) = o;
    }
}

// ====== GEMM2 (MFMA): h2f = fp8(agg1b @ W2), agg1b pre-relu'd; h2f[node][10 u] ======
__global__ __launch_bounds__(256) void gemm2_kernel(const unsigned* __restrict__ agg1b,
                                                    const unsigned* __restrict__ w2t,
                                                    unsigned* __restrict__ h2f) {
    const int wave = threadIdx.x >> 6, lane = threadIdx.x & 63;
    const int nl = lane & 15, quad = lane >> 4;
    const int node = (blockIdx.x * 4 + wave) * 16 + nl;

    v4f c[3];
#pragma unroll
    for (int q = 0; q < 3; ++q) c[q] = (v4f){0.f, 0.f, 0.f, 0.f};

#pragma unroll
    for (int kit = 0; kit < 2; ++kit) {
        U16 bu;
        bu.u = *(const uint4*)(agg1b + (size_t)node * 32 + kit * 16 + quad * 4);
#pragma unroll
        for (int mt = 0; mt < 3; ++mt) {
            U16 au;
            au.u = *(const uint4*)(w2t + ((mt * 16 + nl) * 32 + kit * 16 + quad * 4));
            c[mt] = __builtin_amdgcn_mfma_f32_16x16x32_bf16(au.s, bu.s, c[mt], 0, 0, 0);
        }
    }
    // pack 4 fp8 per uint: uint index = wcol/4 = mt*4+quad (valid < 10)
#pragma unroll
    for (int mt = 0; mt < 3; ++mt) {
        const int idx = mt * 4 + quad;
        if (idx < 10) {
            int u = 0;
            u = __builtin_amdgcn_cvt_pk_fp8_f32(c[mt][0], c[mt][1], u, false);
            u = __builtin_amdgcn_cvt_pk_fp8_f32(c[mt][2], c[mt][3], u, true);
            h2f[(size_t)node * 10 + idx] = (unsigned)u;
        }
    }
}

// ==== SpMM2 gather + log_softmax: fp8 table; 4 nodes/wave, direct col loads ====
// 16 lanes/node: 3 edge slots x 5 lanes x uint2 (8 fp8 ch); chunk = 24 edges.
__global__ void gather40_ls_kernel(const int* __restrict__ rp, const int* __restrict__ col,
                                   const unsigned* __restrict__ h2f,
                                   float* __restrict__ out) {
    const int lane = threadIdx.x & 63;
    const int wave = threadIdx.x >> 6;
    const int sl = lane & 15;
    const int es = sl / 5;            // 0..3 (es==3: lane 15 idle for loads)
    const int cl = sl - es * 5;       // 0..4 (uint2 = 8 fp8 ch)
    const int gbase = lane & 48;      // group base lane (g*16)
    const int node = blockIdx.x * 16 + wave * 4 + (lane >> 4);
    const int b = rp[node], e = rp[node + 1];

    v2f a[4];
#pragma unroll
    for (int k = 0; k < 4; ++k) a[k] = (v2f){0.f, 0.f};

    for (int pos = b; __any(pos < e); pos += 24) {
#pragma unroll
        for (int j = 0; j < 8; ++j) {
            const int ei = pos + j * 3 + es;
            if ((es < 3) && (ei < e)) {
                const int s = col[ei];
                const uint2 v = *(const uint2*)(h2f + (size_t)s * 10 + cl * 2);
                a[0] += __builtin_amdgcn_cvt_pk_f32_fp8((int)v.x, false);
                a[1] += __builtin_amdgcn_cvt_pk_f32_fp8((int)v.x, true);
                a[2] += __builtin_amdgcn_cvt_pk_f32_fp8((int)v.y, false);
                a[3] += __builtin_amdgcn_cvt_pk_f32_fp8((int)v.y, true);
            }
        }
    }
    // fold 3 edge-slots -> lanes sl<5 within each 16-lane group
#pragma unroll
    for (int k = 0; k < 4; ++k) {
#pragma unroll
        for (int h = 0; h < 2; ++h) {
            const float u = __shfl_down(a[k][h], 5, 64);
            const float w = __shfl_down(a[k][h], 10, 64);
            a[k][h] += u + w;
        }
    }

    const bool own = sl < 5;
    float m = -INFINITY;
    if (own) {
#pragma unroll
        for (int k = 0; k < 4; ++k) m = fmaxf(m, fmaxf(a[k][0], a[k][1]));
    }
    const float m0 = __shfl(m, gbase + 0, 64), m1 = __shfl(m, gbase + 1, 64);
    const float m2 = __shfl(m, gbase + 2, 64), m3 = __shfl(m, gbase + 3, 64);
    const float m4 = __shfl(m, gbase + 4, 64);
    const float gm = fmaxf(fmaxf(fmaxf(m0, m1), fmaxf(m2, m3)), m4);

    float s = 0.f;
    if (own) {
#pragma unroll
        for (int k = 0; k < 4; ++k)
            s += __expf(a[k][0] - gm) + __expf(a[k][1] - gm);
    }
    const float s0 = __shfl(s, gbase + 0, 64), s1 = __shfl(s, gbase + 1, 64);
    const float s2 = __shfl(s, gbase + 2, 64), s3 = __shfl(s, gbase + 3, 64);
    const float s4 = __shfl(s, gbase + 4, 64);
    const float ls = __logf(s0 + s1 + s2 + s3 + s4) + gm;

    if (own) {
        float* op = out + (size_t)node * OUT_C + cl * 8;
        *(float4*)op = make_float4(a[0][0] - ls, a[0][1] - ls, a[1][0] - ls, a[1][1] - ls);
        *(float4*)(op + 4) = make_float4(a[2][0] - ls, a[2][1] - ls, a[3][0] - ls, a[3][1] - ls);
    }
}

extern "C" void kernel_launch(void* const* d_in, const int* in_sizes, int n_in,
                              void* d_out, int out_size, void* d_ws, size_t ws_size,
                              hipStream_t stream) {
    const float* x  = (const float*)d_in[0];
    const int* eidx = (const int*)d_in[1];
    const float* W1 = (const float*)d_in[2];
    const float* W2 = (const float*)d_in[3];
    float* out = (float*)d_out;

    const int* src = eidx;             // edge_index[0]
    const int* dst = eidx + N_EDGES;   // edge_index[1]

    // Workspace:
    //   h1b  [80000*32 u32] 10.24 MB (bf16, node-major)
    //   agg1b[80000*32 u32] 10.24 MB (bf16, relu'd)
    //   h2f  [80000*10 u32]  3.20 MB (fp8 e4m3)
    //   gbuf [313*4600], col [1.28M], rp [80001], bcnt [313], w1t, w2t
    unsigned* h1b   = (unsigned*)d_ws;
    unsigned* agg1b = h1b + (size_t)N_NODES * 32;
    unsigned* h2f   = agg1b + (size_t)N_NODES * 32;
    int*      gbuf  = (int*)(h2f + (size_t)N_NODES * 10);
    int*      col   = gbuf + (size_t)KB * BK_CAP;
    int*      rp    = col + N_EDGES;
    int*      bcnt  = rp + (N_NODES + 1);
    unsigned* w1t   = (unsigned*)(bcnt + KB);
    unsigned* w2t   = w1t + 4096;

    // --- prep + [binA || gemm1] + binB ---
    prep_w_kernel<<<16, 256, 0, stream>>>(W1, W2, w1t, w2t, bcnt);
    binA_gemm1_kernel<<<BINA_BLOCKS + GEMM1_BLOCKS, 512, 0, stream>>>(
        src, dst, bcnt, gbuf, x, w1t, h1b);
    binB_kernel<<<KB, 512, 0, stream>>>(bcnt, gbuf, rp, col);

    // --- gathers + gemm2 ---
    gather64_kernel<<<N_NODES / 8, 256, 0, stream>>>(rp, col, h1b, agg1b);
    gemm2_kernel<<<N_NODES / 64, 256, 0, stream>>>(agg1b, w2t, h2f);
    gather40_ls_kernel<<<N_NODES / 16, 256, 0, stream>>>(rp, col, h2f, out);
}

// Round 13
// 186.707 us; speedup vs baseline: 1.0115x; 1.0115x over previous
//
#include <hip/hip_runtime.h>
#include <hip/hip_bf16.h>
#include <math.h>

#define N_NODES 80000
#define N_EDGES 1280000
#define IN_C 128
#define HID_C 64
#define OUT_C 40

// Bucketed counting sort: bucket = dst >> 8 (256 nodes per bucket)
#define KB 313            // ceil(80000 / 256)
#define BK_CAP 4600       // capacity per bucket (mean 4090, sigma ~64 -> 8 sigma)
#define EPT_A 8           // edges per thread in phase A (512 thr -> 4096 per WG)

// ---- bf16 helpers (storage bf16, math fp32) ----
__device__ __forceinline__ float bf_lo(unsigned u) {
    union { unsigned i; float f; } c; c.i = u << 16; return c.f;
}
__device__ __forceinline__ float bf_hi(unsigned u) {
    union { unsigned i; float f; } c; c.i = u & 0xffff0000u; return c.f;
}
__device__ __forceinline__ unsigned pack_bf2(float a, float b) {  // RTNE
    union { float f; unsigned i; } ca, cb; ca.f = a; cb.f = b;
    unsigned ra = (ca.i + 0x7fffu + ((ca.i >> 16) & 1u)) >> 16;
    unsigned rb = (cb.i + 0x7fffu + ((cb.i >> 16) & 1u)) >> 16;
    return ra | (rb << 16);
}

typedef short v8s __attribute__((ext_vector_type(8)));   // 8 bf16 = 4 VGPR
typedef float v4f __attribute__((ext_vector_type(4)));
typedef float v2f __attribute__((ext_vector_type(2)));
union U16 { uint4 u; v8s s; };

__device__ __forceinline__ v2f bf2f(unsigned u) {        // unpack pair -> float2
    return (v2f){bf_lo(u), bf_hi(u)};
}

// ======== prep: W1^T, W2^T to bf16 + zero bcnt (16 blocks) ========
__global__ void prep_w_kernel(const float* __restrict__ W1, const float* __restrict__ W2,
                              unsigned* __restrict__ w1t, unsigned* __restrict__ w2t,
                              int* __restrict__ bcnt) {
    const int g = blockIdx.x * 256 + threadIdx.x;     // 0..4095
    if (g < KB) bcnt[g] = 0;
    {   // w1t: 4096 entries, one per g
        const int wcol = g >> 6, kk = g & 63;
        w1t[g] = pack_bf2(W1[(2 * kk) * HID_C + wcol], W1[(2 * kk + 1) * HID_C + wcol]);
    }
    if (g < 1536) {   // w2t
        const int wcol = g >> 5, kk = g & 31;
        w2t[g] = (wcol < OUT_C)
            ? pack_bf2(W2[(2 * kk) * OUT_C + wcol], W2[(2 * kk + 1) * OUT_C + wcol])
            : 0u;
    }
}

// ================= Phase A: bin edges by dst>>8, grouped writes =================
__global__ __launch_bounds__(512) void binA_kernel(const int* __restrict__ src,
                                                   const int* __restrict__ dst,
                                                   int* __restrict__ bcnt,
                                                   int* __restrict__ gbuf) {
    __shared__ int lcnt[KB];
    __shared__ int lexcl[KB];
    __shared__ int lbase[KB];
    __shared__ int lcur[KB];
    __shared__ int stage[512 * EPT_A];
    __shared__ int gaddr[512 * EPT_A];
    const int tid = threadIdx.x;

    for (int i = tid; i < KB; i += 512) lcnt[i] = 0;
    __syncthreads();

    const int e0 = blockIdx.x * 512 * EPT_A;
    int my_s[EPT_A], my_b[EPT_A], my_dl[EPT_A];
#pragma unroll
    for (int j = 0; j < EPT_A; ++j) {
        const int e = e0 + j * 512 + tid;
        if (e < N_EDGES) {
            const int d = dst[e];
            my_s[j] = src[e];
            my_b[j] = d >> 8;
            my_dl[j] = d & 255;
            atomicAdd(&lcnt[my_b[j]], 1);
        } else my_b[j] = -1;
    }
    __syncthreads();

    if (tid < KB) lexcl[tid] = lcnt[tid];
    __syncthreads();
    for (int o = 1; o < KB; o <<= 1) {
        int t = (tid < KB && tid >= o) ? lexcl[tid - o] : 0;
        __syncthreads();
        if (tid < KB) lexcl[tid] += t;
        __syncthreads();
    }
    const int total = lexcl[KB - 1];
    if (tid < KB) {
        lexcl[tid] -= lcnt[tid];
        lbase[tid] = (lcnt[tid] > 0) ? atomicAdd(&bcnt[tid], lcnt[tid]) : 0;
        lcur[tid] = 0;
    }
    __syncthreads();

#pragma unroll
    for (int j = 0; j < EPT_A; ++j) {
        if (my_b[j] >= 0) {
            const int b = my_b[j];
            const int r = atomicAdd(&lcur[b], 1);
            const int li = lexcl[b] + r;
            stage[li] = (my_s[j] << 8) | my_dl[j];
            int gp = lbase[b] + r;
            if (gp >= BK_CAP) gp = BK_CAP - 1;
            gaddr[li] = b * BK_CAP + gp;
        }
    }
    __syncthreads();

    for (int i = tid; i < total; i += 512)
        gbuf[gaddr[i]] = stage[i];
}

// ===== Phase B: per-bucket -> rp + col (coalesced); bases scanned in-block =====
__global__ __launch_bounds__(512) void binB_kernel(const int* __restrict__ bcnt,
                                                   const int* __restrict__ gbuf,
                                                   int* __restrict__ rp,
                                                   int* __restrict__ col) {
    __shared__ int sc[KB];
    __shared__ int hist[256];
    __shared__ int excl[256];
    __shared__ int cur[256];
    __shared__ int outb[BK_CAP];
    const int b = blockIdx.x;
    const int tid = threadIdx.x;

    if (tid < KB) sc[tid] = min(bcnt[tid], BK_CAP);
    __syncthreads();
    for (int o = 1; o < KB; o <<= 1) {
        int t = (tid < KB && tid >= o) ? sc[tid - o] : 0;
        __syncthreads();
        if (tid < KB) sc[tid] += t;
        __syncthreads();
    }
    const int n = min(bcnt[b], BK_CAP);
    const int cbase = sc[b] - n;
    const int* __restrict__ my = gbuf + (size_t)b * BK_CAP;

    if (tid < 256) hist[tid] = 0;
    __syncthreads();
    for (int i = tid; i < n; i += 512)
        atomicAdd(&hist[my[i] & 255], 1);
    __syncthreads();

    int h = 0;
    if (tid < 256) { h = hist[tid]; excl[tid] = h; }
    __syncthreads();
    for (int o = 1; o < 256; o <<= 1) {
        int t = (tid < 256 && tid >= o) ? excl[tid - o] : 0;
        __syncthreads();
        if (tid < 256) excl[tid] += t;
        __syncthreads();
    }
    if (tid < 256) {
        const int ex = excl[tid] - h;   // exclusive
        cur[tid] = ex;
        const int node = b * 256 + tid;
        if (node <= N_NODES) rp[node] = cbase + ex;
    }
    __syncthreads();

    for (int i = tid; i < n; i += 512) {
        const int pk = my[i];
        const int pos = atomicAdd(&cur[pk & 255], 1);
        outb[pos] = pk >> 8;
    }
    __syncthreads();
    for (int i = tid; i < n; i += 512)
        col[cbase + i] = outb[i];
}

// ================= GEMM1 (MFMA): h1b = bf16(x @ W1), node-major =================
__global__ __launch_bounds__(256) void gemm1_kernel(const float* __restrict__ x,
                                                    const unsigned* __restrict__ w1t,
                                                    unsigned* __restrict__ h1b) {
    const int wave = threadIdx.x >> 6, lane = threadIdx.x & 63;
    const int nl = lane & 15, quad = lane >> 4;
    const int node = (blockIdx.x * 4 + wave) * 16 + nl;

    v4f acc[4];
#pragma unroll
    for (int q = 0; q < 4; ++q) acc[q] = (v4f){0.f, 0.f, 0.f, 0.f};

#pragma unroll
    for (int kit = 0; kit < 4; ++kit) {
        const float* xp = x + (size_t)node * IN_C + kit * 32 + quad * 8;
        const float4 lo = *(const float4*)xp;
        const float4 hi = *(const float4*)(xp + 4);
        U16 bu;
        bu.u.x = pack_bf2(lo.x, lo.y); bu.u.y = pack_bf2(lo.z, lo.w);
        bu.u.z = pack_bf2(hi.x, hi.y); bu.u.w = pack_bf2(hi.z, hi.w);
#pragma unroll
        for (int mt = 0; mt < 4; ++mt) {
            U16 au;
            au.u = *(const uint4*)(w1t + ((mt * 16 + nl) * 64 + kit * 16 + quad * 4));
            acc[mt] = __builtin_amdgcn_mfma_f32_16x16x32_bf16(au.s, bu.s, acc[mt], 0, 0, 0);
        }
    }
#pragma unroll
    for (int mt = 0; mt < 4; ++mt) {
        uint2 o;
        o.x = pack_bf2(acc[mt][0], acc[mt][1]);
        o.y = pack_bf2(acc[mt][2], acc[mt][3]);
        *(uint2*)(h1b + (size_t)node * 32 + mt * 8 + quad * 2) = o;
    }
}

// ===== SpMM1 gather: 2 nodes/wave (32 lanes = 4 edge slots x 8 lanes x uint4) =====
// Direct per-lane col loads (same-address merge) -> 8 independent col->h1 chains.
__global__ void gather64_kernel(const int* __restrict__ rp, const int* __restrict__ col,
                                const unsigned* __restrict__ h1b,
                                unsigned* __restrict__ agg1b) {
    const int lane = threadIdx.x & 63;
    const int wave = threadIdx.x >> 6;
    const int sl = lane & 31;          // sub-lane within node group
    const int es = sl >> 3;            // edge slot 0..3
    const int cl = sl & 7;             // channel group (uint4 = 8 ch)
    const int node = blockIdx.x * 8 + wave * 2 + (lane >> 5);
    const int b = rp[node], e = rp[node + 1];

    v2f acc[4];
#pragma unroll
    for (int k = 0; k < 4; ++k) acc[k] = (v2f){0.f, 0.f};

    for (int pos = b; __any(pos < e); pos += 32) {
#pragma unroll
        for (int j = 0; j < 8; ++j) {
            const int ei = pos + (j << 2) + es;
            if (ei < e) {
                const int s = col[ei];
                const uint4 v = *(const uint4*)(h1b + (size_t)s * 32 + cl * 4);
                acc[0] += bf2f(v.x); acc[1] += bf2f(v.y);
                acc[2] += bf2f(v.z); acc[3] += bf2f(v.w);
            }
        }
    }
    // fold 4 edge-slots -> slot 0 (lanes sl<8), within each 32-lane group
#pragma unroll
    for (int k = 0; k < 4; ++k) {
        acc[k][0] += __shfl_down(acc[k][0], 16, 64);
        acc[k][1] += __shfl_down(acc[k][1], 16, 64);
    }
#pragma unroll
    for (int k = 0; k < 4; ++k) {
        acc[k][0] += __shfl_down(acc[k][0], 8, 64);
        acc[k][1] += __shfl_down(acc[k][1], 8, 64);
    }

    if (sl < 8) {   // relu fused (agg only feeds relu->W2)
        uint4 o;
        o.x = pack_bf2(fmaxf(acc[0][0], 0.f), fmaxf(acc[0][1], 0.f));
        o.y = pack_bf2(fmaxf(acc[1][0], 0.f), fmaxf(acc[1][1], 0.f));
        o.z = pack_bf2(fmaxf(acc[2][0], 0.f), fmaxf(acc[2][1], 0.f));
        o.w = pack_bf2(fmaxf(acc[3][0], 0.f), fmaxf(acc[3][1], 0.f));
        *(uint4*)(agg1b + (size_t)node * 32 + cl * 4) = o;
    }
}

// ====== GEMM2 (MFMA): h2f = fp8(agg1b @ W2), agg1b pre-relu'd; h2f[node][10 u] ======
__global__ __launch_bounds__(256) void gemm2_kernel(const unsigned* __restrict__ agg1b,
                                                    const unsigned* __restrict__ w2t,
                                                    unsigned* __restrict__ h2f) {
    const int wave = threadIdx.x >> 6, lane = threadIdx.x & 63;
    const int nl = lane & 15, quad = lane >> 4;
    const int node = (blockIdx.x * 4 + wave) * 16 + nl;

    v4f c[3];
#pragma unroll
    for (int q = 0; q < 3; ++q) c[q] = (v4f){0.f, 0.f, 0.f, 0.f};

#pragma unroll
    for (int kit = 0; kit < 2; ++kit) {
        U16 bu;
        bu.u = *(const uint4*)(agg1b + (size_t)node * 32 + kit * 16 + quad * 4);
#pragma unroll
        for (int mt = 0; mt < 3; ++mt) {
            U16 au;
            au.u = *(const uint4*)(w2t + ((mt * 16 + nl) * 32 + kit * 16 + quad * 4));
            c[mt] = __builtin_amdgcn_mfma_f32_16x16x32_bf16(au.s, bu.s, c[mt], 0, 0, 0);
        }
    }
    // pack 4 fp8 per uint: uint index = wcol/4 = mt*4+quad (valid < 10)
#pragma unroll
    for (int mt = 0; mt < 3; ++mt) {
        const int idx = mt * 4 + quad;
        if (idx < 10) {
            int u = 0;
            u = __builtin_amdgcn_cvt_pk_fp8_f32(c[mt][0], c[mt][1], u, false);
            u = __builtin_amdgcn_cvt_pk_fp8_f32(c[mt][2], c[mt][3], u, true);
            h2f[(size_t)node * 10 + idx] = (unsigned)u;
        }
    }
}

// ==== SpMM2 gather + log_softmax: fp8 table; 4 nodes/wave, direct col loads ====
// 16 lanes/node: 3 edge slots x 5 lanes x uint2 (8 fp8 ch); chunk = 24 edges.
__global__ void gather40_ls_kernel(const int* __restrict__ rp, const int* __restrict__ col,
                                   const unsigned* __restrict__ h2f,
                                   float* __restrict__ out) {
    const int lane = threadIdx.x & 63;
    const int wave = threadIdx.x >> 6;
    const int sl = lane & 15;
    const int es = sl / 5;            // 0..3 (es==3: lane 15 idle for loads)
    const int cl = sl - es * 5;       // 0..4 (uint2 = 8 fp8 ch)
    const int gbase = lane & 48;      // group base lane (g*16)
    const int node = blockIdx.x * 16 + wave * 4 + (lane >> 4);
    const int b = rp[node], e = rp[node + 1];

    v2f a[4];
#pragma unroll
    for (int k = 0; k < 4; ++k) a[k] = (v2f){0.f, 0.f};

    for (int pos = b; __any(pos < e); pos += 24) {
#pragma unroll
        for (int j = 0; j < 8; ++j) {
            const int ei = pos + j * 3 + es;
            if ((es < 3) && (ei < e)) {
                const int s = col[ei];
                const uint2 v = *(const uint2*)(h2f + (size_t)s * 10 + cl * 2);
                a[0] += __builtin_amdgcn_cvt_pk_f32_fp8((int)v.x, false);
                a[1] += __builtin_amdgcn_cvt_pk_f32_fp8((int)v.x, true);
                a[2] += __builtin_amdgcn_cvt_pk_f32_fp8((int)v.y, false);
                a[3] += __builtin_amdgcn_cvt_pk_f32_fp8((int)v.y, true);
            }
        }
    }
    // fold 3 edge-slots -> lanes sl<5 within each 16-lane group
#pragma unroll
    for (int k = 0; k < 4; ++k) {
#pragma unroll
        for (int h = 0; h < 2; ++h) {
            const float u = __shfl_down(a[k][h], 5, 64);
            const float w = __shfl_down(a[k][h], 10, 64);
            a[k][h] += u + w;
        }
    }

    const bool own = sl < 5;
    float m = -INFINITY;
    if (own) {
#pragma unroll
        for (int k = 0; k < 4; ++k) m = fmaxf(m, fmaxf(a[k][0], a[k][1]));
    }
    const float m0 = __shfl(m, gbase + 0, 64), m1 = __shfl(m, gbase + 1, 64);
    const float m2 = __shfl(m, gbase + 2, 64), m3 = __shfl(m, gbase + 3, 64);
    const float m4 = __shfl(m, gbase + 4, 64);
    const float gm = fmaxf(fmaxf(fmaxf(m0, m1), fmaxf(m2, m3)), m4);

    float s = 0.f;
    if (own) {
#pragma unroll
        for (int k = 0; k < 4; ++k)
            s += __expf(a[k][0] - gm) + __expf(a[k][1] - gm);
    }
    const float s0 = __shfl(s, gbase + 0, 64), s1 = __shfl(s, gbase + 1, 64);
    const float s2 = __shfl(s, gbase + 2, 64), s3 = __shfl(s, gbase + 3, 64);
    const float s4 = __shfl(s, gbase + 4, 64);
    const float ls = __logf(s0 + s1 + s2 + s3 + s4) + gm;

    if (own) {
        float* op = out + (size_t)node * OUT_C + cl * 8;
        *(float4*)op = make_float4(a[0][0] - ls, a[0][1] - ls, a[1][0] - ls, a[1][1] - ls);
        *(float4*)(op + 4) = make_float4(a[2][0] - ls, a[2][1] - ls, a[3][0] - ls, a[3][1] - ls);
    }
}

extern "C" void kernel_launch(void* const* d_in, const int* in_sizes, int n_in,
                              void* d_out, int out_size, void* d_ws, size_t ws_size,
                              hipStream_t stream) {
    const float* x  = (const float*)d_in[0];
    const int* eidx = (const int*)d_in[1];
    const float* W1 = (const float*)d_in[2];
    const float* W2 = (const float*)d_in[3];
    float* out = (float*)d_out;

    const int* src = eidx;             // edge_index[0]
    const int* dst = eidx + N_EDGES;   // edge_index[1]

    // Workspace:
    //   h1b  [80000*32 u32] 10.24 MB (bf16, node-major)
    //   agg1b[80000*32 u32] 10.24 MB (bf16, relu'd)
    //   h2f  [80000*10 u32]  3.20 MB (fp8 e4m3)
    //   gbuf [313*4600], col [1.28M], rp [80001], bcnt [313], w1t, w2t
    unsigned* h1b   = (unsigned*)d_ws;
    unsigned* agg1b = h1b + (size_t)N_NODES * 32;
    unsigned* h2f   = agg1b + (size_t)N_NODES * 32;
    int*      gbuf  = (int*)(h2f + (size_t)N_NODES * 10);
    int*      col   = gbuf + (size_t)KB * BK_CAP;
    int*      rp    = col + N_EDGES;
    int*      bcnt  = rp + (N_NODES + 1);
    unsigned* w1t   = (unsigned*)(bcnt + KB);
    unsigned* w2t   = w1t + 4096;

    // --- prep + CSR build + gemm1 ---
    prep_w_kernel<<<16, 256, 0, stream>>>(W1, W2, w1t, w2t, bcnt);
    binA_kernel<<<(N_EDGES + 512 * EPT_A - 1) / (512 * EPT_A), 512, 0, stream>>>(src, dst, bcnt, gbuf);
    binB_kernel<<<KB, 512, 0, stream>>>(bcnt, gbuf, rp, col);
    gemm1_kernel<<<N_NODES / 64, 256, 0, stream>>>(x, w1t, h1b);

    // --- gathers + gemm2 ---
    gather64_kernel<<<N_NODES / 8, 256, 0, stream>>>(rp, col, h1b, agg1b);
    gemm2_kernel<<<N_NODES / 64, 256, 0, stream>>>(agg1b, w2t, h2f);
    gather40_ls_kernel<<<N_NODES / 16, 256, 0, stream>>>(rp, col, h2f, out);
}

// Round 14
// 181.461 us; speedup vs baseline: 1.0407x; 1.0289x over previous
//
#include <hip/hip_runtime.h>
#include <hip/hip_bf16.h>
#include <math.h>

#define N_NODES 80000
#define N_EDGES 1280000
#define IN_C 128
#define HID_C 64
#define OUT_C 40

// Bucketed counting sort: bucket = dst >> 8 (256 nodes per bucket)
#define KB 313            // ceil(80000 / 256)
#define BK_CAP 4600       // capacity per bucket (mean 4090, sigma ~64 -> 8 sigma)
#define EPT_A 8           // edges per thread in phase A (512 thr -> 4096 per WG)

// ---- bf16 helpers (storage bf16, math fp32) ----
__device__ __forceinline__ float bf_lo(unsigned u) {
    union { unsigned i; float f; } c; c.i = u << 16; return c.f;
}
__device__ __forceinline__ float bf_hi(unsigned u) {
    union { unsigned i; float f; } c; c.i = u & 0xffff0000u; return c.f;
}
__device__ __forceinline__ unsigned pack_bf2(float a, float b) {  // RTNE
    union { float f; unsigned i; } ca, cb; ca.f = a; cb.f = b;
    unsigned ra = (ca.i + 0x7fffu + ((ca.i >> 16) & 1u)) >> 16;
    unsigned rb = (cb.i + 0x7fffu + ((cb.i >> 16) & 1u)) >> 16;
    return ra | (rb << 16);
}

typedef short v8s __attribute__((ext_vector_type(8)));   // 8 bf16 = 4 VGPR
typedef float v4f __attribute__((ext_vector_type(4)));
typedef float v2f __attribute__((ext_vector_type(2)));
union U16 { uint4 u; v8s s; };

__device__ __forceinline__ v2f bf2f(unsigned u) {        // unpack pair -> float2
    return (v2f){bf_lo(u), bf_hi(u)};
}

// ======== prep: W1^T, W2^T to bf16 + zero bcnt (16 blocks) ========
__global__ void prep_w_kernel(const float* __restrict__ W1, const float* __restrict__ W2,
                              unsigned* __restrict__ w1t, unsigned* __restrict__ w2t,
                              int* __restrict__ bcnt) {
    const int g = blockIdx.x * 256 + threadIdx.x;     // 0..4095
    if (g < KB) bcnt[g] = 0;
    {   // w1t: 4096 entries, one per g
        const int wcol = g >> 6, kk = g & 63;
        w1t[g] = pack_bf2(W1[(2 * kk) * HID_C + wcol], W1[(2 * kk + 1) * HID_C + wcol]);
    }
    if (g < 1536) {   // w2t
        const int wcol = g >> 5, kk = g & 31;
        w2t[g] = (wcol < OUT_C)
            ? pack_bf2(W2[(2 * kk) * OUT_C + wcol], W2[(2 * kk + 1) * OUT_C + wcol])
            : 0u;
    }
}

// ================= Phase A: bin edges by dst>>8, grouped writes =================
__global__ __launch_bounds__(512) void binA_kernel(const int* __restrict__ src,
                                                   const int* __restrict__ dst,
                                                   int* __restrict__ bcnt,
                                                   int* __restrict__ gbuf) {
    __shared__ int lcnt[KB];
    __shared__ int lexcl[KB];
    __shared__ int lbase[KB];
    __shared__ int lcur[KB];
    __shared__ int stage[512 * EPT_A];
    __shared__ int gaddr[512 * EPT_A];
    const int tid = threadIdx.x;

    for (int i = tid; i < KB; i += 512) lcnt[i] = 0;
    __syncthreads();

    const int e0 = blockIdx.x * 512 * EPT_A;
    int my_s[EPT_A], my_b[EPT_A], my_dl[EPT_A];
#pragma unroll
    for (int j = 0; j < EPT_A; ++j) {
        const int e = e0 + j * 512 + tid;
        if (e < N_EDGES) {
            const int d = dst[e];
            my_s[j] = src[e];
            my_b[j] = d >> 8;
            my_dl[j] = d & 255;
            atomicAdd(&lcnt[my_b[j]], 1);
        } else my_b[j] = -1;
    }
    __syncthreads();

    if (tid < KB) lexcl[tid] = lcnt[tid];
    __syncthreads();
    for (int o = 1; o < KB; o <<= 1) {
        int t = (tid < KB && tid >= o) ? lexcl[tid - o] : 0;
        __syncthreads();
        if (tid < KB) lexcl[tid] += t;
        __syncthreads();
    }
    const int total = lexcl[KB - 1];
    if (tid < KB) {
        lexcl[tid] -= lcnt[tid];
        lbase[tid] = (lcnt[tid] > 0) ? atomicAdd(&bcnt[tid], lcnt[tid]) : 0;
        lcur[tid] = 0;
    }
    __syncthreads();

#pragma unroll
    for (int j = 0; j < EPT_A; ++j) {
        if (my_b[j] >= 0) {
            const int b = my_b[j];
            const int r = atomicAdd(&lcur[b], 1);
            const int li = lexcl[b] + r;
            stage[li] = (my_s[j] << 8) | my_dl[j];
            int gp = lbase[b] + r;
            if (gp >= BK_CAP) gp = BK_CAP - 1;
            gaddr[li] = b * BK_CAP + gp;
        }
    }
    __syncthreads();

    for (int i = tid; i < total; i += 512)
        gbuf[gaddr[i]] = stage[i];
}

// ===== Phase B: per-bucket -> rp + col (coalesced); bases scanned in-block =====
__global__ __launch_bounds__(512) void binB_kernel(const int* __restrict__ bcnt,
                                                   const int* __restrict__ gbuf,
                                                   int* __restrict__ rp,
                                                   int* __restrict__ col) {
    __shared__ int sc[KB];
    __shared__ int hist[256];
    __shared__ int excl[256];
    __shared__ int cur[256];
    __shared__ int outb[BK_CAP];
    const int b = blockIdx.x;
    const int tid = threadIdx.x;

    if (tid < KB) sc[tid] = min(bcnt[tid], BK_CAP);
    __syncthreads();
    for (int o = 1; o < KB; o <<= 1) {
        int t = (tid < KB && tid >= o) ? sc[tid - o] : 0;
        __syncthreads();
        if (tid < KB) sc[tid] += t;
        __syncthreads();
    }
    const int n = min(bcnt[b], BK_CAP);
    const int cbase = sc[b] - n;
    const int* __restrict__ my = gbuf + (size_t)b * BK_CAP;

    if (tid < 256) hist[tid] = 0;
    __syncthreads();
    for (int i = tid; i < n; i += 512)
        atomicAdd(&hist[my[i] & 255], 1);
    __syncthreads();

    int h = 0;
    if (tid < 256) { h = hist[tid]; excl[tid] = h; }
    __syncthreads();
    for (int o = 1; o < 256; o <<= 1) {
        int t = (tid < 256 && tid >= o) ? excl[tid - o] : 0;
        __syncthreads();
        if (tid < 256) excl[tid] += t;
        __syncthreads();
    }
    if (tid < 256) {
        const int ex = excl[tid] - h;   // exclusive
        cur[tid] = ex;
        const int node = b * 256 + tid;
        if (node <= N_NODES) rp[node] = cbase + ex;
    }
    __syncthreads();

    for (int i = tid; i < n; i += 512) {
        const int pk = my[i];
        const int pos = atomicAdd(&cur[pk & 255], 1);
        outb[pos] = pk >> 8;
    }
    __syncthreads();
    for (int i = tid; i < n; i += 512)
        col[cbase + i] = outb[i];
}

// ================= GEMM1 (MFMA): h1b = bf16(x @ W1), node-major =================
__global__ __launch_bounds__(256) void gemm1_kernel(const float* __restrict__ x,
                                                    const unsigned* __restrict__ w1t,
                                                    unsigned* __restrict__ h1b) {
    const int wave = threadIdx.x >> 6, lane = threadIdx.x & 63;
    const int nl = lane & 15, quad = lane >> 4;
    const int node = (blockIdx.x * 4 + wave) * 16 + nl;

    v4f acc[4];
#pragma unroll
    for (int q = 0; q < 4; ++q) acc[q] = (v4f){0.f, 0.f, 0.f, 0.f};

#pragma unroll
    for (int kit = 0; kit < 4; ++kit) {
        const float* xp = x + (size_t)node * IN_C + kit * 32 + quad * 8;
        const float4 lo = *(const float4*)xp;
        const float4 hi = *(const float4*)(xp + 4);
        U16 bu;
        bu.u.x = pack_bf2(lo.x, lo.y); bu.u.y = pack_bf2(lo.z, lo.w);
        bu.u.z = pack_bf2(hi.x, hi.y); bu.u.w = pack_bf2(hi.z, hi.w);
#pragma unroll
        for (int mt = 0; mt < 4; ++mt) {
            U16 au;
            au.u = *(const uint4*)(w1t + ((mt * 16 + nl) * 64 + kit * 16 + quad * 4));
            acc[mt] = __builtin_amdgcn_mfma_f32_16x16x32_bf16(au.s, bu.s, acc[mt], 0, 0, 0);
        }
    }
#pragma unroll
    for (int mt = 0; mt < 4; ++mt) {
        uint2 o;
        o.x = pack_bf2(acc[mt][0], acc[mt][1]);
        o.y = pack_bf2(acc[mt][2], acc[mt][3]);
        *(uint2*)(h1b + (size_t)node * 32 + mt * 8 + quad * 2) = o;
    }
}

// ===== SpMM1 gather: block = 8 nodes; col segment staged to LDS (coalesced) =====
// 2 nodes/wave, 32 lanes/node: 4 edge slots x 8 lanes x uint4; idx from LDS.
__global__ void gather64_kernel(const int* __restrict__ rp, const int* __restrict__ col,
                                const unsigned* __restrict__ h1b,
                                unsigned* __restrict__ agg1b) {
    __shared__ int lcol[768];          // mean 128, 768 = +56 sigma
    const int tid = threadIdx.x;
    const int lane = tid & 63;
    const int wave = tid >> 6;
    const int sl = lane & 31;          // sub-lane within node group
    const int es = sl >> 3;            // edge slot 0..3
    const int cl = sl & 7;             // channel group (uint4 = 8 ch)
    const int nb = blockIdx.x * 8;

    const int seg_b = rp[nb];
    const int seg_n = min(rp[nb + 8] - seg_b, 768);
    for (int i = tid; i < seg_n; i += 256) lcol[i] = col[seg_b + i];
    __syncthreads();

    const int node = nb + wave * 2 + (lane >> 5);
    const int b = rp[node], e = rp[node + 1];

    v2f acc[4];
#pragma unroll
    for (int k = 0; k < 4; ++k) acc[k] = (v2f){0.f, 0.f};

    for (int pos = b; __any(pos < e); pos += 32) {
#pragma unroll
        for (int j = 0; j < 8; ++j) {
            const int ei = pos + (j << 2) + es;
            if (ei < e) {
                const int o = ei - seg_b;
                const int s = (o < seg_n) ? lcol[o] : col[ei];
                const uint4 v = *(const uint4*)(h1b + (size_t)s * 32 + cl * 4);
                acc[0] += bf2f(v.x); acc[1] += bf2f(v.y);
                acc[2] += bf2f(v.z); acc[3] += bf2f(v.w);
            }
        }
    }
    // fold 4 edge-slots -> slot 0 (lanes sl<8), within each 32-lane group
#pragma unroll
    for (int k = 0; k < 4; ++k) {
        acc[k][0] += __shfl_down(acc[k][0], 16, 64);
        acc[k][1] += __shfl_down(acc[k][1], 16, 64);
    }
#pragma unroll
    for (int k = 0; k < 4; ++k) {
        acc[k][0] += __shfl_down(acc[k][0], 8, 64);
        acc[k][1] += __shfl_down(acc[k][1], 8, 64);
    }

    if (sl < 8) {   // relu fused (agg only feeds relu->W2)
        uint4 o;
        o.x = pack_bf2(fmaxf(acc[0][0], 0.f), fmaxf(acc[0][1], 0.f));
        o.y = pack_bf2(fmaxf(acc[1][0], 0.f), fmaxf(acc[1][1], 0.f));
        o.z = pack_bf2(fmaxf(acc[2][0], 0.f), fmaxf(acc[2][1], 0.f));
        o.w = pack_bf2(fmaxf(acc[3][0], 0.f), fmaxf(acc[3][1], 0.f));
        *(uint4*)(agg1b + (size_t)node * 32 + cl * 4) = o;
    }
}

// ====== GEMM2 (MFMA): h2f = fp8(agg1b @ W2), agg1b pre-relu'd; h2f[node][10 u] ======
__global__ __launch_bounds__(256) void gemm2_kernel(const unsigned* __restrict__ agg1b,
                                                    const unsigned* __restrict__ w2t,
                                                    unsigned* __restrict__ h2f) {
    const int wave = threadIdx.x >> 6, lane = threadIdx.x & 63;
    const int nl = lane & 15, quad = lane >> 4;
    const int node = (blockIdx.x * 4 + wave) * 16 + nl;

    v4f c[3];
#pragma unroll
    for (int q = 0; q < 3; ++q) c[q] = (v4f){0.f, 0.f, 0.f, 0.f};

#pragma unroll
    for (int kit = 0; kit < 2; ++kit) {
        U16 bu;
        bu.u = *(const uint4*)(agg1b + (size_t)node * 32 + kit * 16 + quad * 4);
#pragma unroll
        for (int mt = 0; mt < 3; ++mt) {
            U16 au;
            au.u = *(const uint4*)(w2t + ((mt * 16 + nl) * 32 + kit * 16 + quad * 4));
            c[mt] = __builtin_amdgcn_mfma_f32_16x16x32_bf16(au.s, bu.s, c[mt], 0, 0, 0);
        }
    }
    // pack 4 fp8 per uint: uint index = wcol/4 = mt*4+quad (valid < 10)
#pragma unroll
    for (int mt = 0; mt < 3; ++mt) {
        const int idx = mt * 4 + quad;
        if (idx < 10) {
            int u = 0;
            u = __builtin_amdgcn_cvt_pk_fp8_f32(c[mt][0], c[mt][1], u, false);
            u = __builtin_amdgcn_cvt_pk_fp8_f32(c[mt][2], c[mt][3], u, true);
            h2f[(size_t)node * 10 + idx] = (unsigned)u;
        }
    }
}

// ==== SpMM2 gather + log_softmax: fp8 table; block = 16 nodes, LDS col staging ====
// 4 nodes/wave, 16 lanes/node: 3 edge slots x 5 lanes x uint2 (8 fp8 ch).
__global__ void gather40_ls_kernel(const int* __restrict__ rp, const int* __restrict__ col,
                                   const unsigned* __restrict__ h2f,
                                   float* __restrict__ out) {
    __shared__ int lcol[1024];         // mean 256, 1024 = +48 sigma
    const int tid = threadIdx.x;
    const int lane = tid & 63;
    const int wave = tid >> 6;
    const int sl = lane & 15;
    const int es = sl / 5;            // 0..3 (es==3: lane 15 idle for loads)
    const int cl = sl - es * 5;       // 0..4 (uint2 = 8 fp8 ch)
    const int gbase = lane & 48;      // group base lane (g*16)
    const int nb = blockIdx.x * 16;

    const int seg_b = rp[nb];
    const int seg_n = min(rp[nb + 16] - seg_b, 1024);
    for (int i = tid; i < seg_n; i += 256) lcol[i] = col[seg_b + i];
    __syncthreads();

    const int node = nb + wave * 4 + (lane >> 4);
    const int b = rp[node], e = rp[node + 1];

    v2f a[4];
#pragma unroll
    for (int k = 0; k < 4; ++k) a[k] = (v2f){0.f, 0.f};

    for (int pos = b; __any(pos < e); pos += 24) {
#pragma unroll
        for (int j = 0; j < 8; ++j) {
            const int ei = pos + j * 3 + es;
            if ((es < 3) && (ei < e)) {
                const int o = ei - seg_b;
                const int s = (o < seg_n) ? lcol[o] : col[ei];
                const uint2 v = *(const uint2*)(h2f + (size_t)s * 10 + cl * 2);
                a[0] += __builtin_amdgcn_cvt_pk_f32_fp8((int)v.x, false);
                a[1] += __builtin_amdgcn_cvt_pk_f32_fp8((int)v.x, true);
                a[2] += __builtin_amdgcn_cvt_pk_f32_fp8((int)v.y, false);
                a[3] += __builtin_amdgcn_cvt_pk_f32_fp8((int)v.y, true);
            }
        }
    }
    // fold 3 edge-slots -> lanes sl<5 within each 16-lane group
#pragma unroll
    for (int k = 0; k < 4; ++k) {
#pragma unroll
        for (int h = 0; h < 2; ++h) {
            const float u = __shfl_down(a[k][h], 5, 64);
            const float w = __shfl_down(a[k][h], 10, 64);
            a[k][h] += u + w;
        }
    }

    const bool own = sl < 5;
    float m = -INFINITY;
    if (own) {
#pragma unroll
        for (int k = 0; k < 4; ++k) m = fmaxf(m, fmaxf(a[k][0], a[k][1]));
    }
    const float m0 = __shfl(m, gbase + 0, 64), m1 = __shfl(m, gbase + 1, 64);
    const float m2 = __shfl(m, gbase + 2, 64), m3 = __shfl(m, gbase + 3, 64);
    const float m4 = __shfl(m, gbase + 4, 64);
    const float gm = fmaxf(fmaxf(fmaxf(m0, m1), fmaxf(m2, m3)), m4);

    float s = 0.f;
    if (own) {
#pragma unroll
        for (int k = 0; k < 4; ++k)
            s += __expf(a[k][0] - gm) + __expf(a[k][1] - gm);
    }
    const float s0 = __shfl(s, gbase + 0, 64), s1 = __shfl(s, gbase + 1, 64);
    const float s2 = __shfl(s, gbase + 2, 64), s3 = __shfl(s, gbase + 3, 64);
    const float s4 = __shfl(s, gbase + 4, 64);
    const float ls = __logf(s0 + s1 + s2 + s3 + s4) + gm;

    if (own) {
        float* op = out + (size_t)node * OUT_C + cl * 8;
        *(float4*)op = make_float4(a[0][0] - ls, a[0][1] - ls, a[1][0] - ls, a[1][1] - ls);
        *(float4*)(op + 4) = make_float4(a[2][0] - ls, a[2][1] - ls, a[3][0] - ls, a[3][1] - ls);
    }
}

extern "C" void kernel_launch(void* const* d_in, const int* in_sizes, int n_in,
                              void* d_out, int out_size, void* d_ws, size_t ws_size,
                              hipStream_t stream) {
    const float* x  = (const float*)d_in[0];
    const int* eidx = (const int*)d_in[1];
    const float* W1 = (const float*)d_in[2];
    const float* W2 = (const float*)d_in[3];
    float* out = (float*)d_out;

    const int* src = eidx;             // edge_index[0]
    const int* dst = eidx + N_EDGES;   // edge_index[1]

    // Workspace:
    //   h1b  [80000*32 u32] 10.24 MB (bf16, node-major)
    //   agg1b[80000*32 u32] 10.24 MB (bf16, relu'd)
    //   h2f  [80000*10 u32]  3.20 MB (fp8 e4m3)
    //   gbuf [313*4600], col [1.28M], rp [80001], bcnt [313], w1t, w2t
    unsigned* h1b   = (unsigned*)d_ws;
    unsigned* agg1b = h1b + (size_t)N_NODES * 32;
    unsigned* h2f   = agg1b + (size_t)N_NODES * 32;
    int*      gbuf  = (int*)(h2f + (size_t)N_NODES * 10);
    int*      col   = gbuf + (size_t)KB * BK_CAP;
    int*      rp    = col + N_EDGES;
    int*      bcnt  = rp + (N_NODES + 1);
    unsigned* w1t   = (unsigned*)(bcnt + KB);
    unsigned* w2t   = w1t + 4096;

    // --- prep + CSR build + gemm1 ---
    prep_w_kernel<<<16, 256, 0, stream>>>(W1, W2, w1t, w2t, bcnt);
    binA_kernel<<<(N_EDGES + 512 * EPT_A - 1) / (512 * EPT_A), 512, 0, stream>>>(src, dst, bcnt, gbuf);
    binB_kernel<<<KB, 512, 0, stream>>>(bcnt, gbuf, rp, col);
    gemm1_kernel<<<N_NODES / 64, 256, 0, stream>>>(x, w1t, h1b);

    // --- gathers + gemm2 ---
    gather64_kernel<<<N_NODES / 8, 256, 0, stream>>>(rp, col, h1b, agg1b);
    gemm2_kernel<<<N_NODES / 64, 256, 0, stream>>>(agg1b, w2t, h2f);
    gather40_ls_kernel<<<N_NODES / 16, 256, 0, stream>>>(rp, col, h2f, out);
}